// Round 1
// baseline (232.616 us; speedup 1.0000x reference)
//
#include <hip/hip_runtime.h>

// FilterAugment: out[b,0,f,t] = x[b,0,f,t] * 10^(gain_db[b,f]/20)
// gain_db[b,f] = piecewise-linear interp of band_factors[b, 0..4] over
// frequency bands given by band_bndry_freqs = [0, 57, 121, 188, 256].
//
// B=64, F=256, T=2048. Memory-bound: 128 MiB in + 128 MiB out => ~43 us at
// 6.3 TB/s achievable.

#define B_DIM 64
#define F_DIM 256
#define T_DIM 2048
#define N_BAND 4

// One block per (b,f) row. All gain math is blockIdx-uniform => scalarized.
// 256 threads x 2 float4 = 512 float4 = 2048 floats = one row.
__global__ __launch_bounds__(256) void filter_augment_kernel(
    const float4* __restrict__ x,            // [B,1,F,T] as float4
    const float* __restrict__ band_factors,  // [B, N_BAND+1]
    const int* __restrict__ bndry,           // [N_BAND+1]
    float4* __restrict__ out)                // [B,1,F,T] as float4
{
    const int blk = blockIdx.x;      // blk = b * F_DIM + f
    const int b = blk >> 8;          // F_DIM = 256
    const int f = blk & (F_DIM - 1);

    // searchsorted(bndry, f, side='right') - 1, clipped to [0, N_BAND-1].
    // bndry[0] = 0 <= f always, so idx = (# of bndry[1..N_BAND] <= f).
    int idx = 0;
#pragma unroll
    for (int k = 1; k <= N_BAND; ++k) {
        idx += (bndry[k] <= f) ? 1 : 0;
    }
    if (idx > N_BAND - 1) idx = N_BAND - 1;

    const int lo    = bndry[idx];
    const int width = bndry[idx + 1] - lo;
    const int denom = (width - 1 > 1) ? (width - 1) : 1;
    const float t   = (float)(f - lo) / (float)denom;

    const float g0 = band_factors[b * (N_BAND + 1) + idx];
    const float g1 = band_factors[b * (N_BAND + 1) + idx + 1];
    const float gain_db = g0 + (g1 - g0) * t;
    // 10^(g/20) = 2^(g * log2(10)/20)
    const float filt = exp2f(gain_db * 0.16609640474436813f);

    const int base = blk * (T_DIM / 4);  // float4 index; max 2^23, fits int
    const int tid  = threadIdx.x;

    float4 v0 = x[base + tid];
    float4 v1 = x[base + tid + 256];
    v0.x *= filt; v0.y *= filt; v0.z *= filt; v0.w *= filt;
    v1.x *= filt; v1.y *= filt; v1.z *= filt; v1.w *= filt;
    out[base + tid]       = v0;
    out[base + tid + 256] = v1;
}

extern "C" void kernel_launch(void* const* d_in, const int* in_sizes, int n_in,
                              void* d_out, int out_size, void* d_ws, size_t ws_size,
                              hipStream_t stream) {
    const float4* x           = (const float4*)d_in[0];
    const float* band_factors = (const float*)d_in[1];
    const int*   bndry        = (const int*)d_in[2];
    float4* out               = (float4*)d_out;

    const int n_blocks = B_DIM * F_DIM;  // 16384
    filter_augment_kernel<<<n_blocks, 256, 0, stream>>>(x, band_factors, bndry, out);
}

// Round 3
// 221.659 us; speedup vs baseline: 1.0494x; 1.0494x over previous
//
#include <hip/hip_runtime.h>

// FilterAugment: out[b,0,f,t] = x[b,0,f,t] * 10^(gain_db[b,f]/20)
// gain_db[b,f] = piecewise-linear interp of band_factors[b, 0..4] over
// frequency bands given by band_bndry_freqs = [0, 57, 121, 188, 256].
//
// B=64, F=256, T=2048. Memory-bound: 128 MiB in + 128 MiB out => ~40 us at
// the ~6.7 TB/s the harness's own fills achieve on this part.
//
// R2 changes vs R1 (resubmitted in R3 after broker timeout — no measurement
// was taken of this version yet): nontemporal load/store (zero-reuse
// streaming data, skip L2 write-allocate) + 2 rows/block with 4
// float4/thread for more MLP.

#define B_DIM 64
#define F_DIM 256
#define T_DIM 2048
#define N_BAND 4

typedef float f32x4 __attribute__((ext_vector_type(4)));

__device__ __forceinline__ float band_gain(const float* __restrict__ band_factors,
                                           const int* __restrict__ bndry,
                                           int b, int f) {
    // searchsorted(bndry, f, side='right') - 1, clipped to [0, N_BAND-1].
    // bndry[0] = 0 <= f always, so idx = (# of bndry[1..N_BAND] <= f), clipped.
    int idx = 0;
#pragma unroll
    for (int k = 1; k <= N_BAND; ++k) idx += (bndry[k] <= f) ? 1 : 0;
    if (idx > N_BAND - 1) idx = N_BAND - 1;

    const int lo    = bndry[idx];
    const int width = bndry[idx + 1] - lo;
    const int denom = (width - 1 > 1) ? (width - 1) : 1;
    const float t   = (float)(f - lo) / (float)denom;

    const float g0 = band_factors[b * (N_BAND + 1) + idx];
    const float g1 = band_factors[b * (N_BAND + 1) + idx + 1];
    const float gain_db = g0 + (g1 - g0) * t;
    // 10^(g/20) = 2^(g * log2(10)/20)
    return exp2f(gain_db * 0.16609640474436813f);
}

// One block per 2 consecutive (b,f) rows. 256 threads x 4 float4 = 1024
// float4 = 2 rows of 2048 floats. Gain math is blockIdx-uniform (scalarized).
__global__ __launch_bounds__(256) void filter_augment_kernel(
    const f32x4* __restrict__ x,             // [B,1,F,T] as float4
    const float* __restrict__ band_factors,  // [B, N_BAND+1]
    const int* __restrict__ bndry,           // [N_BAND+1]
    f32x4* __restrict__ out)                 // [B,1,F,T] as float4
{
    const int row0 = blockIdx.x * 2;         // row = b * F_DIM + f
    const int b  = row0 >> 8;                // F_DIM = 256
    const int f0 = row0 & (F_DIM - 1);       // even, so f0 and f0+1 share b

    const float filt0 = band_gain(band_factors, bndry, b, f0);
    const float filt1 = band_gain(band_factors, bndry, b, f0 + 1);

    const int tid  = threadIdx.x;
    const int base = row0 * (T_DIM / 4);     // float4 index; max 2^23, fits int

    // Issue all 4 loads before any use: 4 outstanding 16B loads/lane.
    f32x4 a0 = __builtin_nontemporal_load(&x[base + tid]);
    f32x4 a1 = __builtin_nontemporal_load(&x[base + tid + 256]);
    f32x4 b0 = __builtin_nontemporal_load(&x[base + 512 + tid]);
    f32x4 b1 = __builtin_nontemporal_load(&x[base + 512 + tid + 256]);

    a0 *= filt0; a1 *= filt0;
    b0 *= filt1; b1 *= filt1;

    __builtin_nontemporal_store(a0, &out[base + tid]);
    __builtin_nontemporal_store(a1, &out[base + tid + 256]);
    __builtin_nontemporal_store(b0, &out[base + 512 + tid]);
    __builtin_nontemporal_store(b1, &out[base + 512 + tid + 256]);
}

extern "C" void kernel_launch(void* const* d_in, const int* in_sizes, int n_in,
                              void* d_out, int out_size, void* d_ws, size_t ws_size,
                              hipStream_t stream) {
    const f32x4* x            = (const f32x4*)d_in[0];
    const float* band_factors = (const float*)d_in[1];
    const int*   bndry        = (const int*)d_in[2];
    f32x4* out                = (f32x4*)d_out;

    const int n_blocks = (B_DIM * F_DIM) / 2;  // 8192, 2 rows per block
    filter_augment_kernel<<<n_blocks, 256, 0, stream>>>(x, band_factors, bndry, out);
}